// Round 9
// baseline (578.315 us; speedup 1.0000x reference)
//
#include <hip/hip_runtime.h>
#include <hip/hip_bf16.h>

// GATv2 x3 + BN + ReLU + mean-pool + linear.
// MFMA bf16 GEMMs (no LDS, BN+ReLU fused into A-load), fp32 softmax math.
// Aggregation: two-phase (score->LDS, then weighted re-gather) so the inner
// loops have no exp/softmax-update on the cross-iteration dependency chain.
// N=100000 nodes, E=1.6M edges (+N self loops), F=128, H=64/32/16, G=64.

static constexpr int G_ = 64;

typedef short bfrag __attribute__((ext_vector_type(8)));   // 8 bf16 = 4 VGPR
typedef float facc  __attribute__((ext_vector_type(4)));   // 4 f32 acc

// ---------------- bf16 helpers ----------------
__device__ __forceinline__ float asfloat_(unsigned int u) {
  union { unsigned int i; float f; } c; c.i = u; return c.f;
}
__device__ __forceinline__ unsigned short f2bf(float f) {
  union { float f; unsigned int i; } c;
  c.f = f;
  unsigned int r = c.i + 0x7FFFu + ((c.i >> 16) & 1u);  // round-nearest-even
  return (unsigned short)(r >> 16);
}

// load 4 bf16 as fp32 (8B vector load)
__device__ __forceinline__ void load_bf4(const unsigned short* p, float* f) {
  uint2 q = *reinterpret_cast<const uint2*>(p);
  f[0] = asfloat_(q.x << 16); f[1] = asfloat_(q.x & 0xFFFF0000u);
  f[2] = asfloat_(q.y << 16); f[3] = asfloat_(q.y & 0xFFFF0000u);
}

// ---------------- weight packing: Wt[col][k] bf16 (B^T fragment layout) ----
__global__ __launch_bounds__(256) void pack_all(
    const float* __restrict__ Wl1, const float* __restrict__ Wr1,
    const float* __restrict__ bl1, const float* __restrict__ br1,
    const float* __restrict__ Wl2, const float* __restrict__ Wr2,
    const float* __restrict__ bl2, const float* __restrict__ br2,
    const float* __restrict__ Wl3, const float* __restrict__ Wr3,
    const float* __restrict__ bl3, const float* __restrict__ br3,
    unsigned short* __restrict__ Wt1, float* __restrict__ bc1,
    unsigned short* __restrict__ Wt2, float* __restrict__ bc2,
    unsigned short* __restrict__ Wt3, float* __restrict__ bc3) {
  int i = blockIdx.x * 256 + threadIdx.x;
  if (i < 128 * 128) { int c = i >> 7, k = i & 127;
    Wt1[i] = f2bf((c < 64) ? Wl1[k * 64 + c] : Wr1[k * 64 + (c - 64)]); }
  if (i < 128) bc1[i] = (i < 64) ? bl1[i] : br1[i - 64];
  if (i < 64 * 64) { int c = i >> 6, k = i & 63;
    Wt2[i] = f2bf((c < 32) ? Wl2[k * 32 + c] : Wr2[k * 32 + (c - 32)]); }
  if (i < 64) bc2[i] = (i < 32) ? bl2[i] : br2[i - 32];
  if (i < 32 * 32) { int c = i >> 5, k = i & 31;
    Wt3[i] = f2bf((c < 16) ? Wl3[k * 16 + c] : Wr3[k * 16 + (c - 16)]); }
  if (i < 32) bc3[i] = (i < 16) ? bl3[i] : br3[i - 16];
}

// ---------------- CSR build (XCD-partitioned by dst range) ----------------
__global__ __launch_bounds__(256) void edge_hist(
    const int* __restrict__ ei, int* __restrict__ deg, int E, int Etot, int N) {
  int p = blockIdx.x & 7;
  int q = blockIdx.x >> 3;
  int nbq = gridDim.x >> 3;
  float scale = 8.0f / (float)N;
  for (int i = q * 256 + threadIdx.x; i < Etot; i += nbq * 256) {
    int dst = (i < E) ? ei[E + i] : (i - E);
    int pp = min((int)((float)dst * scale), 7);
    if (pp == p) atomicAdd(&deg[dst], 1);
  }
}

__global__ __launch_bounds__(256) void scan1(
    const int* __restrict__ deg, int* __restrict__ part, int* __restrict__ bsums, int n) {
  __shared__ int ts[256];
  int t = threadIdx.x, b = blockIdx.x;
  int base = b * 1024 + t * 4;
  int d[4];
#pragma unroll
  for (int q = 0; q < 4; q++) d[q] = (base + q < n) ? deg[base + q] : 0;
  int s = d[0] + d[1] + d[2] + d[3];
  ts[t] = s;
  __syncthreads();
  for (int o = 1; o < 256; o <<= 1) {
    int v = (t >= o) ? ts[t - o] : 0;
    __syncthreads();
    ts[t] += v;
    __syncthreads();
  }
  int incl = ts[t];
  if (t == 255) bsums[b] = incl;
  int run = incl - s;
#pragma unroll
  for (int q = 0; q < 4; q++) {
    if (base + q < n) part[base + q] = run;
    run += d[q];
  }
}

__global__ void scan2(int* bsums, int nb) {
  __shared__ int s[256];
  int t = threadIdx.x;
  int v = (t < nb) ? bsums[t] : 0;
  s[t] = v;
  __syncthreads();
  for (int o = 1; o < 256; o <<= 1) {
    int u = (t >= o) ? s[t - o] : 0;
    __syncthreads();
    s[t] += u;
    __syncthreads();
  }
  if (t < nb) bsums[t] = s[t] - v;  // exclusive
}

__global__ __launch_bounds__(256) void scan3(
    int* __restrict__ rp, int* __restrict__ cur, const int* __restrict__ bsums,
    int n, int Etot) {
  int i = blockIdx.x * 256 + threadIdx.x;
  if (i < n) {
    int v = rp[i] + bsums[i >> 10];
    rp[i] = v; cur[i] = v;
  }
  if (i == 0) rp[n] = Etot;
}

__global__ __launch_bounds__(256) void scatter_edges(
    const int* __restrict__ ei, int* __restrict__ cur, int* __restrict__ ssrc,
    int E, int Etot, int N) {
  int p = blockIdx.x & 7;
  int q = blockIdx.x >> 3;
  int nbq = gridDim.x >> 3;
  float scale = 8.0f / (float)N;
  for (int i = q * 256 + threadIdx.x; i < Etot; i += nbq * 256) {
    int dst = (i < E) ? ei[E + i] : (i - E);
    int pp = min((int)((float)dst * scale), 7);
    if (pp != p) continue;
    int src = (i < E) ? ei[i] : (i - E);
    int pos = atomicAdd(&cur[dst], 1);
    ssrc[pos] = src;
  }
}

// ---------------- MFMA GEMM: [XL|XR][N][H] = A[N][FI] @ Wt^T + bcat -------
// AMODE 0: A bf16. AMODE 1: A fp32 -> bf16. AMODE 2: A fp32 + BN + ReLU.
// Output split: cols [0,H) -> XL, [H,2H) -> XR (both bf16, [N][H]).
template <int FI, int FO, int AMODE>
__global__ __launch_bounds__(256) void gemm_mfma(
    const void* __restrict__ Ain, const float* __restrict__ ssb,
    const unsigned short* __restrict__ Wt, const float* __restrict__ bcat,
    unsigned short* __restrict__ XL, unsigned short* __restrict__ XR, int N) {
  constexpr int NT = FO / 16;
  constexpr int KS = FI / 32;
  constexpr int H = FO / 2;
  int tid = threadIdx.x;
  int w = tid >> 6;
  int lr = tid & 15;
  int lg = (tid & 63) >> 4;
  int n0 = blockIdx.x * 64;
  int arow = min(n0 + w * 16 + lr, N - 1);  // clamp reads; stores masked

  facc acc[NT];
#pragma unroll
  for (int t = 0; t < NT; t++)
#pragma unroll
    for (int e = 0; e < 4; e++) acc[t][e] = 0.f;

#pragma unroll
  for (int ks = 0; ks < KS; ks++) {
    int k0 = ks * 32 + lg * 8;
    bfrag a;
    if constexpr (AMODE == 0) {
      const unsigned short* Ab = (const unsigned short*)Ain;
      a = *reinterpret_cast<const bfrag*>(&Ab[(size_t)arow * FI + k0]);
    } else {
      const float* Af = (const float*)Ain;
      const float* p = &Af[(size_t)arow * FI + k0];
      float4 lo = *reinterpret_cast<const float4*>(p);
      float4 hi = *reinterpret_cast<const float4*>(p + 4);
      float f[8] = {lo.x, lo.y, lo.z, lo.w, hi.x, hi.y, hi.z, hi.w};
      if constexpr (AMODE == 2) {
        float4 sc0 = *reinterpret_cast<const float4*>(&ssb[k0]);
        float4 sc1 = *reinterpret_cast<const float4*>(&ssb[k0 + 4]);
        float4 sh0 = *reinterpret_cast<const float4*>(&ssb[FI + k0]);
        float4 sh1 = *reinterpret_cast<const float4*>(&ssb[FI + k0 + 4]);
        float sc[8] = {sc0.x, sc0.y, sc0.z, sc0.w, sc1.x, sc1.y, sc1.z, sc1.w};
        float sh[8] = {sh0.x, sh0.y, sh0.z, sh0.w, sh1.x, sh1.y, sh1.z, sh1.w};
#pragma unroll
        for (int e = 0; e < 8; e++) f[e] = fmaxf(fmaf(f[e], sc[e], sh[e]), 0.f);
      }
      union { bfrag v; unsigned short u[8]; } cv;
#pragma unroll
      for (int e = 0; e < 8; e++) cv.u[e] = f2bf(f[e]);
      a = cv.v;
    }
#pragma unroll
    for (int t = 0; t < NT; t++) {
      bfrag b = *reinterpret_cast<const bfrag*>(&Wt[(size_t)(t * 16 + lr) * FI + k0]);
      acc[t] = __builtin_amdgcn_mfma_f32_16x16x32_bf16(a, b, acc[t], 0, 0, 0);
    }
  }

#pragma unroll
  for (int t = 0; t < NT; t++) {
    int col = t * 16 + lr;
    float bias = bcat[col];
    unsigned short* dstbuf = (t < NT / 2) ? XL : XR;
    int cc = (t < NT / 2) ? col : (col - H);
#pragma unroll
    for (int r = 0; r < 4; r++) {
      int n = n0 + w * 16 + lg * 4 + r;
      if (n < N) dstbuf[(size_t)n * H + cc] = f2bf(acc[t][r] + bias);
    }
  }
}

// ---------------- GATv2 aggregation v5: two-phase, scores staged in LDS ---
__device__ __forceinline__ float lrelu02(float z) {
  return fmaxf(z, 0.2f * z);
}

template <int H>
__global__ __launch_bounds__(256) void gat_agg5(
    const unsigned short* __restrict__ XL, const unsigned short* __restrict__ XR,
    const float* __restrict__ att, const float* __restrict__ bias,
    const int* __restrict__ rp, const int* __restrict__ ssrc,
    float* __restrict__ out, int N) {
  constexpr int L = H / 4;            // lanes per edge
  constexpr int C = 64 / L;           // concurrent edges per wave
  constexpr int CHUNK = 128;
  __shared__ float ts[4][CHUNK];
  int wv = threadIdx.x >> 6;
  int v = blockIdx.x * 4 + wv;
  if (v >= N) return;
  int lane = threadIdx.x & 63;
  int fl = lane % L;                  // feature block [fl*4, fl*4+4)
  int sub = lane / L;                 // edge slot

  float xr[4];
  load_bf4(&XR[(size_t)v * H + fl * 4], xr);
  const float4 a4 = *reinterpret_cast<const float4*>(&att[fl * 4]);
  int beg = rp[v], end = rp[v + 1];

  float m = -3.0e38f, d = 0.f, acc[4] = {0.f, 0.f, 0.f, 0.f};

  for (int c0 = beg; c0 < end; c0 += CHUNK) {
    int n = min(CHUNK, end - c0);

    // phase A: scores -> LDS; only cross-iteration dep is fmax
    float mc = -3.0e38f;
    for (int k = sub; k < n; k += C) {
      int u = ssrc[c0 + k];
      float xl[4];
      load_bf4(&XL[(size_t)u * H + fl * 4], xl);
      float t = a4.x * lrelu02(xl[0] + xr[0]);
      t = fmaf(a4.y, lrelu02(xl[1] + xr[1]), t);
      t = fmaf(a4.z, lrelu02(xl[2] + xr[2]), t);
      t = fmaf(a4.w, lrelu02(xl[3] + xr[3]), t);
#pragma unroll
      for (int o = L / 2; o >= 1; o >>= 1) t += __shfl_xor(t, o);
      mc = fmaxf(mc, t);
      if (fl == 0) ts[wv][k] = t;
    }
    // chunk max across slots
#pragma unroll
    for (int o = L; o < 64; o <<= 1) mc = fmaxf(mc, __shfl_xor(mc, o));

    // merge into running state
    float mn = fmaxf(m, mc);
    float sc = __expf(m - mn);
    d *= sc;
#pragma unroll
    for (int e = 0; e < 4; e++) acc[e] *= sc;
    m = mn;

    // w-pass: one exp per edge, wave-parallel; d via butterfly
    float dl = 0.f;
    for (int k = lane; k < n; k += 64) {
      float w = __expf(ts[wv][k] - m);
      ts[wv][k] = w;
      dl += w;
    }
#pragma unroll
    for (int o = 1; o < 64; o <<= 1) dl += __shfl_xor(dl, o);
    d += dl;

    // phase B: weighted re-gather (L2-hot); chain is a single fma
    for (int k = sub; k < n; k += C) {
      float wgt = ts[wv][k];
      int u = ssrc[c0 + k];
      float xl[4];
      load_bf4(&XL[(size_t)u * H + fl * 4], xl);
#pragma unroll
      for (int e = 0; e < 4; e++) acc[e] = fmaf(wgt, xl[e], acc[e]);
    }
  }

  // sum acc across slots (same m everywhere -> plain sum)
#pragma unroll
  for (int o = L; o < 64; o <<= 1) {
#pragma unroll
    for (int e = 0; e < 4; e++) acc[e] += __shfl_xor(acc[e], o);
  }

  if (lane < L) {
    float inv = 1.f / (d + 1e-16f);
    const float4 b4 = *reinterpret_cast<const float4*>(&bias[fl * 4]);
    float4 o4 = make_float4(fmaf(acc[0], inv, b4.x), fmaf(acc[1], inv, b4.y),
                            fmaf(acc[2], inv, b4.z), fmaf(acc[3], inv, b4.w));
    *reinterpret_cast<float4*>(&out[(size_t)v * H + fl * 4]) = o4;
  }
}

// ---------------- BatchNorm ----------------
template <int H>
__global__ __launch_bounds__(256) void bn_stats(
    const float* __restrict__ X, float* __restrict__ stats, int N) {
  __shared__ float ls[256], ls2[256];
  int tid = threadIdx.x;
  int h = tid % H;
  constexpr int RPB = 256 / H;
  int r0 = blockIdx.x * RPB + tid / H;
  float s = 0.f, s2 = 0.f;
  for (int n = r0; n < N; n += gridDim.x * RPB) {
    float val = X[(size_t)n * H + h];
    s += val; s2 += val * val;
  }
  ls[tid] = s; ls2[tid] = s2;
  __syncthreads();
  if (tid < H) {
    for (int g = 1; g < RPB; g++) { s += ls[tid + g * H]; s2 += ls2[tid + g * H]; }
    atomicAdd(&stats[h], s);
    atomicAdd(&stats[H + h], s2);
  }
}

__global__ void bn_finalize(
    const float* __restrict__ stats, const float* __restrict__ gamma,
    const float* __restrict__ beta, float* __restrict__ ss, int H, int N) {
  int h = threadIdx.x;
  if (h < H) {
    float mean = stats[h] / (float)N;
    float var = stats[H + h] / (float)N - mean * mean;
    float istd = rsqrtf(var + 1e-5f);
    float sc = gamma[h] * istd;
    ss[h] = sc;
    ss[H + h] = beta[h] - mean * sc;
  }
}

// ---------------- fused BN+ReLU + mean-pool, then final linear ------------
__global__ __launch_bounds__(256) void pool_kernel(
    const float* __restrict__ X, const float* __restrict__ ss,
    const int* __restrict__ batch, float* __restrict__ pool,
    float* __restrict__ cnt, int N) {
  __shared__ float lp[G_ * 16];
  __shared__ float lc[G_];
  int tid = threadIdx.x;
  for (int j = tid; j < G_ * 16; j += 256) lp[j] = 0.f;
  if (tid < G_) lc[tid] = 0.f;
  __syncthreads();
  int tot = N * 16;
  for (int i = blockIdx.x * 256 + tid; i < tot; i += gridDim.x * 256) {
    int n = i >> 4, h = i & 15;
    int g = batch[n];
    float t = X[i] * ss[h] + ss[16 + h];
    t = (t > 0.f) ? t : 0.f;
    atomicAdd(&lp[g * 16 + h], t);
    if (h == 0) atomicAdd(&lc[g], 1.0f);
  }
  __syncthreads();
  for (int j = tid; j < G_ * 16; j += 256) atomicAdd(&pool[j], lp[j]);
  if (tid < G_) atomicAdd(&cnt[tid], lc[tid]);
}

__global__ void final_linear(
    const float* __restrict__ pool, const float* __restrict__ cnt,
    const float* __restrict__ linW, const float* __restrict__ linb,
    float* __restrict__ out) {
  int g = threadIdx.x;
  if (g < G_) {
    float c = fmaxf(cnt[g], 1.0f);
    float acc = 0.f;
    for (int h = 0; h < 16; h++) acc += (pool[g * 16 + h] / c) * linW[h];
    out[g] = acc + linb[0];
  }
}

// ---------------- launch ----------------
extern "C" void kernel_launch(void* const* d_in, const int* in_sizes, int n_in,
                              void* d_out, int out_size, void* d_ws, size_t ws_size,
                              hipStream_t stream) {
  const float* x = (const float*)d_in[0];
  const int* ei = (const int*)d_in[1];
  const int* batch = (const int*)d_in[2];
  const int N = in_sizes[0] / 128;
  const int E = in_sizes[1] / 2;
  const int Etot = E + N;

  char* wsb = (char*)d_ws;
  size_t off = 0;
  auto alloc = [&](size_t bytes) -> void* {
    void* p = wsb + off;
    off += (bytes + 255) & ~(size_t)255;
    return p;
  };
  unsigned short* XLb = (unsigned short*)alloc((size_t)64 * N * 2);  // xl bf16
  unsigned short* XRb = (unsigned short*)alloc((size_t)64 * N * 2);  // xr bf16
  float* R2 = (float*)alloc((size_t)64 * N * 4);                     // agg out fp32
  int* row_ptr = (int*)alloc((size_t)(N + 1) * 4);
  int* cursor = (int*)alloc((size_t)N * 4);
  int* bsums = (int*)alloc(4096);
  int* ssrc = (int*)alloc((size_t)Etot * 4);
  unsigned short* Wt1 = (unsigned short*)alloc(16384 * 2);
  float* bc1 = (float*)alloc(128 * 4);
  unsigned short* Wt2 = (unsigned short*)alloc(4096 * 2);
  float* bc2 = (float*)alloc(64 * 4);
  unsigned short* Wt3 = (unsigned short*)alloc(1024 * 2);
  float* bc3 = (float*)alloc(32 * 4);
  float* ss = (float*)alloc(256 * 4);
  // single zeroed region: deg[N] | stats1[128] | stats2[128] | stats3[128] | pool | cnt
  size_t zelems = (size_t)N + 3 * 128 + G_ * 16 + G_;
  char* zb = (char*)alloc(zelems * 4);
  int* deg = (int*)zb;
  float* stats1 = (float*)(zb + (size_t)N * 4);
  float* stats2 = stats1 + 128;
  float* stats3 = stats2 + 128;
  float* pool = stats3 + 128;
  float* cnt = pool + G_ * 16;

  const float* Wl1 = (const float*)d_in[3];  const float* bl1 = (const float*)d_in[4];
  const float* Wr1 = (const float*)d_in[5];  const float* br1 = (const float*)d_in[6];
  const float* att1 = (const float*)d_in[7]; const float* bias1 = (const float*)d_in[8];
  const float* g1 = (const float*)d_in[9];   const float* b1 = (const float*)d_in[10];
  const float* Wl2 = (const float*)d_in[11]; const float* bl2 = (const float*)d_in[12];
  const float* Wr2 = (const float*)d_in[13]; const float* br2 = (const float*)d_in[14];
  const float* att2 = (const float*)d_in[15]; const float* bias2 = (const float*)d_in[16];
  const float* g2 = (const float*)d_in[17];  const float* b2 = (const float*)d_in[18];
  const float* Wl3 = (const float*)d_in[19]; const float* bl3 = (const float*)d_in[20];
  const float* Wr3 = (const float*)d_in[21]; const float* br3 = (const float*)d_in[22];
  const float* att3 = (const float*)d_in[23]; const float* bias3 = (const float*)d_in[24];
  const float* g3 = (const float*)d_in[25];  const float* b3 = (const float*)d_in[26];
  const float* linW = (const float*)d_in[27]; const float* linb = (const float*)d_in[28];
  float* out = (float*)d_out;

  int nb = (N + 1023) / 1024;
  int nnodeblk = (N + 3) / 4;
  int ngemm = (N + 63) / 64;

  // weights + zero scratch
  pack_all<<<64, 256, 0, stream>>>(Wl1, Wr1, bl1, br1, Wl2, Wr2, bl2, br2,
                                   Wl3, Wr3, bl3, br3, Wt1, bc1, Wt2, bc2, Wt3, bc3);
  hipMemsetAsync(zb, 0, zelems * 4, stream);

  // CSR build (XCD-partitioned hist + scatter)
  edge_hist<<<4096, 256, 0, stream>>>(ei, deg, E, Etot, N);
  scan1<<<nb, 256, 0, stream>>>(deg, row_ptr, bsums, N);
  scan2<<<1, 256, 0, stream>>>(bsums, nb);
  scan3<<<(N + 255) / 256, 256, 0, stream>>>(row_ptr, cursor, bsums, N, Etot);
  scatter_edges<<<4096, 256, 0, stream>>>(ei, cursor, ssrc, E, Etot, N);

  // ---- layer 1 ----
  gemm_mfma<128, 128, 1><<<ngemm, 256, 0, stream>>>(x, nullptr, Wt1, bc1, XLb, XRb, N);
  gat_agg5<64><<<nnodeblk, 256, 0, stream>>>(XLb, XRb, att1, bias1, row_ptr, ssrc, R2, N);
  bn_stats<64><<<512, 256, 0, stream>>>(R2, stats1, N);
  bn_finalize<<<1, 64, 0, stream>>>(stats1, g1, b1, ss, 64, N);

  // ---- layer 2 (BN+ReLU fused into GEMM A-load) ----
  gemm_mfma<64, 64, 2><<<ngemm, 256, 0, stream>>>(R2, ss, Wt2, bc2, XLb, XRb, N);
  gat_agg5<32><<<nnodeblk, 256, 0, stream>>>(XLb, XRb, att2, bias2, row_ptr, ssrc, R2, N);
  bn_stats<32><<<512, 256, 0, stream>>>(R2, stats2, N);
  bn_finalize<<<1, 64, 0, stream>>>(stats2, g2, b2, ss, 32, N);

  // ---- layer 3 ----
  gemm_mfma<32, 32, 2><<<ngemm, 256, 0, stream>>>(R2, ss, Wt3, bc3, XLb, XRb, N);
  gat_agg5<16><<<nnodeblk, 256, 0, stream>>>(XLb, XRb, att3, bias3, row_ptr, ssrc, R2, N);
  bn_stats<16><<<512, 256, 0, stream>>>(R2, stats3, N);
  bn_finalize<<<1, 64, 0, stream>>>(stats3, g3, b3, ss, 16, N);

  // ---- fused BN+ReLU+pool + linear ----
  pool_kernel<<<2048, 256, 0, stream>>>(R2, ss, batch, pool, cnt, N);
  final_linear<<<1, 64, 0, stream>>>(pool, cnt, linW, linb, out);
}

// Round 10
// 502.432 us; speedup vs baseline: 1.1510x; 1.1510x over previous
//
#include <hip/hip_runtime.h>
#include <hip/hip_bf16.h>

// GATv2 x3 + BN + ReLU + mean-pool + linear.
// MFMA bf16 GEMMs (no LDS, BN+ReLU fused into A-load), fp32 softmax math.
// Aggregation: single-pass, register-buffered chunks (gathers batched and
// independent; exp/softmax update moved off the load-dependency chain).
// N=100000 nodes, E=1.6M edges (+N self loops), F=128, H=64/32/16, G=64.

static constexpr int G_ = 64;

typedef short bfrag __attribute__((ext_vector_type(8)));   // 8 bf16 = 4 VGPR
typedef float facc  __attribute__((ext_vector_type(4)));   // 4 f32 acc

// ---------------- bf16 helpers ----------------
__device__ __forceinline__ float asfloat_(unsigned int u) {
  union { unsigned int i; float f; } c; c.i = u; return c.f;
}
__device__ __forceinline__ unsigned short f2bf(float f) {
  union { float f; unsigned int i; } c;
  c.f = f;
  unsigned int r = c.i + 0x7FFFu + ((c.i >> 16) & 1u);  // round-nearest-even
  return (unsigned short)(r >> 16);
}

// load 4 bf16 as fp32 (8B vector load)
__device__ __forceinline__ void load_bf4(const unsigned short* p, float* f) {
  uint2 q = *reinterpret_cast<const uint2*>(p);
  f[0] = asfloat_(q.x << 16); f[1] = asfloat_(q.x & 0xFFFF0000u);
  f[2] = asfloat_(q.y << 16); f[3] = asfloat_(q.y & 0xFFFF0000u);
}

// ---------------- weight packing: Wt[col][k] bf16 (B^T fragment layout) ----
__global__ __launch_bounds__(256) void pack_all(
    const float* __restrict__ Wl1, const float* __restrict__ Wr1,
    const float* __restrict__ bl1, const float* __restrict__ br1,
    const float* __restrict__ Wl2, const float* __restrict__ Wr2,
    const float* __restrict__ bl2, const float* __restrict__ br2,
    const float* __restrict__ Wl3, const float* __restrict__ Wr3,
    const float* __restrict__ bl3, const float* __restrict__ br3,
    unsigned short* __restrict__ Wt1, float* __restrict__ bc1,
    unsigned short* __restrict__ Wt2, float* __restrict__ bc2,
    unsigned short* __restrict__ Wt3, float* __restrict__ bc3) {
  int i = blockIdx.x * 256 + threadIdx.x;
  if (i < 128 * 128) { int c = i >> 7, k = i & 127;
    Wt1[i] = f2bf((c < 64) ? Wl1[k * 64 + c] : Wr1[k * 64 + (c - 64)]); }
  if (i < 128) bc1[i] = (i < 64) ? bl1[i] : br1[i - 64];
  if (i < 64 * 64) { int c = i >> 6, k = i & 63;
    Wt2[i] = f2bf((c < 32) ? Wl2[k * 32 + c] : Wr2[k * 32 + (c - 32)]); }
  if (i < 64) bc2[i] = (i < 32) ? bl2[i] : br2[i - 32];
  if (i < 32 * 32) { int c = i >> 5, k = i & 31;
    Wt3[i] = f2bf((c < 16) ? Wl3[k * 16 + c] : Wr3[k * 16 + (c - 16)]); }
  if (i < 32) bc3[i] = (i < 16) ? bl3[i] : br3[i - 16];
}

// ---------------- CSR build (XCD-partitioned by dst range) ----------------
__global__ __launch_bounds__(256) void edge_hist(
    const int* __restrict__ ei, int* __restrict__ deg, int E, int Etot, int N) {
  int p = blockIdx.x & 7;
  int q = blockIdx.x >> 3;
  int nbq = gridDim.x >> 3;
  float scale = 8.0f / (float)N;
  for (int i = q * 256 + threadIdx.x; i < Etot; i += nbq * 256) {
    int dst = (i < E) ? ei[E + i] : (i - E);
    int pp = min((int)((float)dst * scale), 7);
    if (pp == p) atomicAdd(&deg[dst], 1);
  }
}

__global__ __launch_bounds__(256) void scan1(
    const int* __restrict__ deg, int* __restrict__ part, int* __restrict__ bsums, int n) {
  __shared__ int ts[256];
  int t = threadIdx.x, b = blockIdx.x;
  int base = b * 1024 + t * 4;
  int d[4];
#pragma unroll
  for (int q = 0; q < 4; q++) d[q] = (base + q < n) ? deg[base + q] : 0;
  int s = d[0] + d[1] + d[2] + d[3];
  ts[t] = s;
  __syncthreads();
  for (int o = 1; o < 256; o <<= 1) {
    int v = (t >= o) ? ts[t - o] : 0;
    __syncthreads();
    ts[t] += v;
    __syncthreads();
  }
  int incl = ts[t];
  if (t == 255) bsums[b] = incl;
  int run = incl - s;
#pragma unroll
  for (int q = 0; q < 4; q++) {
    if (base + q < n) part[base + q] = run;
    run += d[q];
  }
}

__global__ void scan2(int* bsums, int nb) {
  __shared__ int s[256];
  int t = threadIdx.x;
  int v = (t < nb) ? bsums[t] : 0;
  s[t] = v;
  __syncthreads();
  for (int o = 1; o < 256; o <<= 1) {
    int u = (t >= o) ? s[t - o] : 0;
    __syncthreads();
    s[t] += u;
    __syncthreads();
  }
  if (t < nb) bsums[t] = s[t] - v;  // exclusive
}

__global__ __launch_bounds__(256) void scan3(
    int* __restrict__ rp, int* __restrict__ cur, const int* __restrict__ bsums,
    int n, int Etot) {
  int i = blockIdx.x * 256 + threadIdx.x;
  if (i < n) {
    int v = rp[i] + bsums[i >> 10];
    rp[i] = v; cur[i] = v;
  }
  if (i == 0) rp[n] = Etot;
}

__global__ __launch_bounds__(256) void scatter_edges(
    const int* __restrict__ ei, int* __restrict__ cur, int* __restrict__ ssrc,
    int E, int Etot, int N) {
  int p = blockIdx.x & 7;
  int q = blockIdx.x >> 3;
  int nbq = gridDim.x >> 3;
  float scale = 8.0f / (float)N;
  for (int i = q * 256 + threadIdx.x; i < Etot; i += nbq * 256) {
    int dst = (i < E) ? ei[E + i] : (i - E);
    int pp = min((int)((float)dst * scale), 7);
    if (pp != p) continue;
    int src = (i < E) ? ei[i] : (i - E);
    int pos = atomicAdd(&cur[dst], 1);
    ssrc[pos] = src;
  }
}

// ---------------- MFMA GEMM: [XL|XR][N][H] = A[N][FI] @ Wt^T + bcat -------
// AMODE 0: A bf16. AMODE 1: A fp32 -> bf16. AMODE 2: A fp32 + BN + ReLU.
// Output split: cols [0,H) -> XL, [H,2H) -> XR (both bf16, [N][H]).
template <int FI, int FO, int AMODE>
__global__ __launch_bounds__(256) void gemm_mfma(
    const void* __restrict__ Ain, const float* __restrict__ ssb,
    const unsigned short* __restrict__ Wt, const float* __restrict__ bcat,
    unsigned short* __restrict__ XL, unsigned short* __restrict__ XR, int N) {
  constexpr int NT = FO / 16;
  constexpr int KS = FI / 32;
  constexpr int H = FO / 2;
  int tid = threadIdx.x;
  int w = tid >> 6;
  int lr = tid & 15;
  int lg = (tid & 63) >> 4;
  int n0 = blockIdx.x * 64;
  int arow = min(n0 + w * 16 + lr, N - 1);  // clamp reads; stores masked

  facc acc[NT];
#pragma unroll
  for (int t = 0; t < NT; t++)
#pragma unroll
    for (int e = 0; e < 4; e++) acc[t][e] = 0.f;

#pragma unroll
  for (int ks = 0; ks < KS; ks++) {
    int k0 = ks * 32 + lg * 8;
    bfrag a;
    if constexpr (AMODE == 0) {
      const unsigned short* Ab = (const unsigned short*)Ain;
      a = *reinterpret_cast<const bfrag*>(&Ab[(size_t)arow * FI + k0]);
    } else {
      const float* Af = (const float*)Ain;
      const float* p = &Af[(size_t)arow * FI + k0];
      float4 lo = *reinterpret_cast<const float4*>(p);
      float4 hi = *reinterpret_cast<const float4*>(p + 4);
      float f[8] = {lo.x, lo.y, lo.z, lo.w, hi.x, hi.y, hi.z, hi.w};
      if constexpr (AMODE == 2) {
        float4 sc0 = *reinterpret_cast<const float4*>(&ssb[k0]);
        float4 sc1 = *reinterpret_cast<const float4*>(&ssb[k0 + 4]);
        float4 sh0 = *reinterpret_cast<const float4*>(&ssb[FI + k0]);
        float4 sh1 = *reinterpret_cast<const float4*>(&ssb[FI + k0 + 4]);
        float sc[8] = {sc0.x, sc0.y, sc0.z, sc0.w, sc1.x, sc1.y, sc1.z, sc1.w};
        float sh[8] = {sh0.x, sh0.y, sh0.z, sh0.w, sh1.x, sh1.y, sh1.z, sh1.w};
#pragma unroll
        for (int e = 0; e < 8; e++) f[e] = fmaxf(fmaf(f[e], sc[e], sh[e]), 0.f);
      }
      union { bfrag v; unsigned short u[8]; } cv;
#pragma unroll
      for (int e = 0; e < 8; e++) cv.u[e] = f2bf(f[e]);
      a = cv.v;
    }
#pragma unroll
    for (int t = 0; t < NT; t++) {
      bfrag b = *reinterpret_cast<const bfrag*>(&Wt[(size_t)(t * 16 + lr) * FI + k0]);
      acc[t] = __builtin_amdgcn_mfma_f32_16x16x32_bf16(a, b, acc[t], 0, 0, 0);
    }
  }

#pragma unroll
  for (int t = 0; t < NT; t++) {
    int col = t * 16 + lr;
    float bias = bcat[col];
    unsigned short* dstbuf = (t < NT / 2) ? XL : XR;
    int cc = (t < NT / 2) ? col : (col - H);
#pragma unroll
    for (int r = 0; r < 4; r++) {
      int n = n0 + w * 16 + lg * 4 + r;
      if (n < N) dstbuf[(size_t)n * H + cc] = f2bf(acc[t][r] + bias);
    }
  }
}

// ---------------- GATv2 aggregation v6: register-buffered chunks ----------
__device__ __forceinline__ float lrelu02(float z) {
  return fmaxf(z, 0.2f * z);
}

template <int H, int ITER>
__global__ __launch_bounds__(256) void gat_agg6(
    const unsigned short* __restrict__ XL, const unsigned short* __restrict__ XR,
    const float* __restrict__ att, const float* __restrict__ bias,
    const int* __restrict__ rp, const int* __restrict__ ssrc,
    float* __restrict__ out, int N) {
  constexpr int L = H / 4;            // lanes per edge
  constexpr int C = 64 / L;           // concurrent edges per wave
  constexpr int CHUNK = C * ITER;
  int v = blockIdx.x * 4 + (threadIdx.x >> 6);
  if (v >= N) return;
  int lane = threadIdx.x & 63;
  int fl = lane % L;                  // feature block [fl*4, fl*4+4)
  int sub = lane / L;                 // edge slot

  float xr[4];
  load_bf4(&XR[(size_t)v * H + fl * 4], xr);
  const float4 a4 = *reinterpret_cast<const float4*>(&att[fl * 4]);
  int beg = rp[v], end = rp[v + 1];

  float m = -3.0e38f, d = 0.f, acc[4] = {0.f, 0.f, 0.f, 0.f};

  for (int cb = beg; cb < end; cb += CHUNK) {
    // --- load + score: ITER independent gathers per lane, only fmax on the
    // cross-iteration chain; exp/update deferred to the register phase.
    float xb[ITER][4];
    float tl[ITER];
    float mc = -3.0e38f;
#pragma unroll
    for (int it = 0; it < ITER; it++) {
      int j = cb + it * C + sub;
      bool valid = (j < end);
      int jj = valid ? j : (end - 1);
      int u = ssrc[jj];
      load_bf4(&XL[(size_t)u * H + fl * 4], xb[it]);
      float t = a4.x * lrelu02(xb[it][0] + xr[0]);
      t = fmaf(a4.y, lrelu02(xb[it][1] + xr[1]), t);
      t = fmaf(a4.z, lrelu02(xb[it][2] + xr[2]), t);
      t = fmaf(a4.w, lrelu02(xb[it][3] + xr[3]), t);
#pragma unroll
      for (int o = L / 2; o >= 1; o >>= 1) t += __shfl_xor(t, o);
      tl[it] = valid ? t : -3.0e38f;
      mc = fmaxf(mc, tl[it]);
    }
    // chunk max across slots
#pragma unroll
    for (int o = L; o < 64; o <<= 1) mc = fmaxf(mc, __shfl_xor(mc, o));

    // rescale running state once per chunk
    float mn = fmaxf(m, mc);
    float sc = __expf(m - mn);
    d *= sc;
#pragma unroll
    for (int e = 0; e < 4; e++) acc[e] *= sc;
    m = mn;

    // accumulate from registers (pure VALU)
#pragma unroll
    for (int it = 0; it < ITER; it++) {
      float w = __expf(tl[it] - m);   // 0 for masked slots
      d += w;
#pragma unroll
      for (int e = 0; e < 4; e++) acc[e] = fmaf(w, xb[it][e], acc[e]);
    }
  }

  // butterfly sums across slots (shared m -> plain sums)
#pragma unroll
  for (int o = L; o < 64; o <<= 1) {
    d += __shfl_xor(d, o);
#pragma unroll
    for (int e = 0; e < 4; e++) acc[e] += __shfl_xor(acc[e], o);
  }

  if (lane < L) {
    float inv = 1.f / (d + 1e-16f);
    const float4 b4 = *reinterpret_cast<const float4*>(&bias[fl * 4]);
    float4 o4 = make_float4(fmaf(acc[0], inv, b4.x), fmaf(acc[1], inv, b4.y),
                            fmaf(acc[2], inv, b4.z), fmaf(acc[3], inv, b4.w));
    *reinterpret_cast<float4*>(&out[(size_t)v * H + fl * 4]) = o4;
  }
}

// ---------------- BatchNorm ----------------
template <int H>
__global__ __launch_bounds__(256) void bn_stats(
    const float* __restrict__ X, float* __restrict__ stats, int N) {
  __shared__ float ls[256], ls2[256];
  int tid = threadIdx.x;
  int h = tid % H;
  constexpr int RPB = 256 / H;
  int r0 = blockIdx.x * RPB + tid / H;
  float s = 0.f, s2 = 0.f;
  for (int n = r0; n < N; n += gridDim.x * RPB) {
    float val = X[(size_t)n * H + h];
    s += val; s2 += val * val;
  }
  ls[tid] = s; ls2[tid] = s2;
  __syncthreads();
  if (tid < H) {
    for (int g = 1; g < RPB; g++) { s += ls[tid + g * H]; s2 += ls2[tid + g * H]; }
    atomicAdd(&stats[h], s);
    atomicAdd(&stats[H + h], s2);
  }
}

__global__ void bn_finalize(
    const float* __restrict__ stats, const float* __restrict__ gamma,
    const float* __restrict__ beta, float* __restrict__ ss, int H, int N) {
  int h = threadIdx.x;
  if (h < H) {
    float mean = stats[h] / (float)N;
    float var = stats[H + h] / (float)N - mean * mean;
    float istd = rsqrtf(var + 1e-5f);
    float sc = gamma[h] * istd;
    ss[h] = sc;
    ss[H + h] = beta[h] - mean * sc;
  }
}

// ---------------- fused BN+ReLU + mean-pool, then final linear ------------
__global__ __launch_bounds__(256) void pool_kernel(
    const float* __restrict__ X, const float* __restrict__ ss,
    const int* __restrict__ batch, float* __restrict__ pool,
    float* __restrict__ cnt, int N) {
  __shared__ float lp[G_ * 16];
  __shared__ float lc[G_];
  int tid = threadIdx.x;
  for (int j = tid; j < G_ * 16; j += 256) lp[j] = 0.f;
  if (tid < G_) lc[tid] = 0.f;
  __syncthreads();
  int tot = N * 16;
  for (int i = blockIdx.x * 256 + tid; i < tot; i += gridDim.x * 256) {
    int n = i >> 4, h = i & 15;
    int g = batch[n];
    float t = X[i] * ss[h] + ss[16 + h];
    t = (t > 0.f) ? t : 0.f;
    atomicAdd(&lp[g * 16 + h], t);
    if (h == 0) atomicAdd(&lc[g], 1.0f);
  }
  __syncthreads();
  for (int j = tid; j < G_ * 16; j += 256) atomicAdd(&pool[j], lp[j]);
  if (tid < G_) atomicAdd(&cnt[tid], lc[tid]);
}

__global__ void final_linear(
    const float* __restrict__ pool, const float* __restrict__ cnt,
    const float* __restrict__ linW, const float* __restrict__ linb,
    float* __restrict__ out) {
  int g = threadIdx.x;
  if (g < G_) {
    float c = fmaxf(cnt[g], 1.0f);
    float acc = 0.f;
    for (int h = 0; h < 16; h++) acc += (pool[g * 16 + h] / c) * linW[h];
    out[g] = acc + linb[0];
  }
}

// ---------------- launch ----------------
extern "C" void kernel_launch(void* const* d_in, const int* in_sizes, int n_in,
                              void* d_out, int out_size, void* d_ws, size_t ws_size,
                              hipStream_t stream) {
  const float* x = (const float*)d_in[0];
  const int* ei = (const int*)d_in[1];
  const int* batch = (const int*)d_in[2];
  const int N = in_sizes[0] / 128;
  const int E = in_sizes[1] / 2;
  const int Etot = E + N;

  char* wsb = (char*)d_ws;
  size_t off = 0;
  auto alloc = [&](size_t bytes) -> void* {
    void* p = wsb + off;
    off += (bytes + 255) & ~(size_t)255;
    return p;
  };
  unsigned short* XLb = (unsigned short*)alloc((size_t)64 * N * 2);  // xl bf16
  unsigned short* XRb = (unsigned short*)alloc((size_t)64 * N * 2);  // xr bf16
  float* R2 = (float*)alloc((size_t)64 * N * 4);                     // agg out fp32
  int* row_ptr = (int*)alloc((size_t)(N + 1) * 4);
  int* cursor = (int*)alloc((size_t)N * 4);
  int* bsums = (int*)alloc(4096);
  int* ssrc = (int*)alloc((size_t)Etot * 4);
  unsigned short* Wt1 = (unsigned short*)alloc(16384 * 2);
  float* bc1 = (float*)alloc(128 * 4);
  unsigned short* Wt2 = (unsigned short*)alloc(4096 * 2);
  float* bc2 = (float*)alloc(64 * 4);
  unsigned short* Wt3 = (unsigned short*)alloc(1024 * 2);
  float* bc3 = (float*)alloc(32 * 4);
  float* ss = (float*)alloc(256 * 4);
  // single zeroed region: deg[N] | stats1[128] | stats2[128] | stats3[128] | pool | cnt
  size_t zelems = (size_t)N + 3 * 128 + G_ * 16 + G_;
  char* zb = (char*)alloc(zelems * 4);
  int* deg = (int*)zb;
  float* stats1 = (float*)(zb + (size_t)N * 4);
  float* stats2 = stats1 + 128;
  float* stats3 = stats2 + 128;
  float* pool = stats3 + 128;
  float* cnt = pool + G_ * 16;

  const float* Wl1 = (const float*)d_in[3];  const float* bl1 = (const float*)d_in[4];
  const float* Wr1 = (const float*)d_in[5];  const float* br1 = (const float*)d_in[6];
  const float* att1 = (const float*)d_in[7]; const float* bias1 = (const float*)d_in[8];
  const float* g1 = (const float*)d_in[9];   const float* b1 = (const float*)d_in[10];
  const float* Wl2 = (const float*)d_in[11]; const float* bl2 = (const float*)d_in[12];
  const float* Wr2 = (const float*)d_in[13]; const float* br2 = (const float*)d_in[14];
  const float* att2 = (const float*)d_in[15]; const float* bias2 = (const float*)d_in[16];
  const float* g2 = (const float*)d_in[17];  const float* b2 = (const float*)d_in[18];
  const float* Wl3 = (const float*)d_in[19]; const float* bl3 = (const float*)d_in[20];
  const float* Wr3 = (const float*)d_in[21]; const float* br3 = (const float*)d_in[22];
  const float* att3 = (const float*)d_in[23]; const float* bias3 = (const float*)d_in[24];
  const float* g3 = (const float*)d_in[25];  const float* b3 = (const float*)d_in[26];
  const float* linW = (const float*)d_in[27]; const float* linb = (const float*)d_in[28];
  float* out = (float*)d_out;

  int nb = (N + 1023) / 1024;
  int nnodeblk = (N + 3) / 4;
  int ngemm = (N + 63) / 64;

  // weights + zero scratch
  pack_all<<<64, 256, 0, stream>>>(Wl1, Wr1, bl1, br1, Wl2, Wr2, bl2, br2,
                                   Wl3, Wr3, bl3, br3, Wt1, bc1, Wt2, bc2, Wt3, bc3);
  hipMemsetAsync(zb, 0, zelems * 4, stream);

  // CSR build (XCD-partitioned hist + scatter)
  edge_hist<<<4096, 256, 0, stream>>>(ei, deg, E, Etot, N);
  scan1<<<nb, 256, 0, stream>>>(deg, row_ptr, bsums, N);
  scan2<<<1, 256, 0, stream>>>(bsums, nb);
  scan3<<<(N + 255) / 256, 256, 0, stream>>>(row_ptr, cursor, bsums, N, Etot);
  scatter_edges<<<4096, 256, 0, stream>>>(ei, cursor, ssrc, E, Etot, N);

  // ---- layer 1 ----
  gemm_mfma<128, 128, 1><<<ngemm, 256, 0, stream>>>(x, nullptr, Wt1, bc1, XLb, XRb, N);
  gat_agg6<64, 6><<<nnodeblk, 256, 0, stream>>>(XLb, XRb, att1, bias1, row_ptr, ssrc, R2, N);
  bn_stats<64><<<512, 256, 0, stream>>>(R2, stats1, N);
  bn_finalize<<<1, 64, 0, stream>>>(stats1, g1, b1, ss, 64, N);

  // ---- layer 2 (BN+ReLU fused into GEMM A-load) ----
  gemm_mfma<64, 64, 2><<<ngemm, 256, 0, stream>>>(R2, ss, Wt2, bc2, XLb, XRb, N);
  gat_agg6<32, 4><<<nnodeblk, 256, 0, stream>>>(XLb, XRb, att2, bias2, row_ptr, ssrc, R2, N);
  bn_stats<32><<<512, 256, 0, stream>>>(R2, stats2, N);
  bn_finalize<<<1, 64, 0, stream>>>(stats2, g2, b2, ss, 32, N);

  // ---- layer 3 ----
  gemm_mfma<32, 32, 2><<<ngemm, 256, 0, stream>>>(R2, ss, Wt3, bc3, XLb, XRb, N);
  gat_agg6<16, 2><<<nnodeblk, 256, 0, stream>>>(XLb, XRb, att3, bias3, row_ptr, ssrc, R2, N);
  bn_stats<16><<<512, 256, 0, stream>>>(R2, stats3, N);
  bn_finalize<<<1, 64, 0, stream>>>(stats3, g3, b3, ss, 16, N);

  // ---- fused BN+ReLU+pool + linear ----
  pool_kernel<<<2048, 256, 0, stream>>>(R2, ss, batch, pool, cnt, N);
  final_linear<<<1, 64, 0, stream>>>(pool, cnt, linW, linb, out);
}